// Round 8
// baseline (127.022 us; speedup 1.0000x reference)
//
#include <hip/hip_runtime.h>
#include <hip/hip_fp16.h>
#include <stdint.h>

// ---------------------------------------------------------------------------
// ThreeBodyLayer fused kernel v7 (MI355X / gfx950)
//
// All-f16 MFMA pipeline, log2-domain softplus. Scale algebra: W1/b1 carry
// log2(e); W2 carries ln2*log2(e)=1; b2*log2(e); W3*ln2.
//
// v7 vs v6 (42.7us, VALU 48%, occ 69%):
//  - u-row ds_reads hoisted out of the Phase-2 loop (loop-invariant)
//  - Phase-2 loop made uniformly 4 iterations, fully unrolled, with masked
//    accumulation (q>=30 -> 0) => no wave-uniform break, 4-deep pipelining
//  - b1 bias folded into MFMA C-init in Phase 1
// ---------------------------------------------------------------------------

typedef __attribute__((ext_vector_type(8))) _Float16 f16x8;
typedef __attribute__((ext_vector_type(2))) __fp16   fp16v2;   // cvt_pkrtz ret
typedef __attribute__((ext_vector_type(4))) float    f32x4;
typedef __attribute__((ext_vector_type(4))) unsigned int u32x4;

constexpr int   BPB       = 32;       // batch elems per block
constexpr int   NT        = 1024;     // 16 waves
constexpr int   T_STRIDE  = 1680;     // bytes per b: 13*128 + 16 pad
constexpr int   WT_RS     = 72;       // padded f16 row stride in LDS
constexpr int   WT_OFF    = BPB * T_STRIDE;          // 53760
constexpr int   Y_OFF     = WT_OFF + 192 * WT_RS * 2; // 81408
constexpr int   LDS_BYTES = Y_OFF + 128;             // 81536 -> 2 blocks/CU

// d_ws layout (bytes)
constexpr int   WS_W1T   = 0;         // 12288 f16 compact: (slab*64+n)*64 + d
constexpr int   WS_W2T   = 24576;     //  2048 f16 : m*64 + k
constexpr int   WS_B1    = 28672;     //    64 f32 : b1 * L2E
constexpr int   WS_B2    = 28928;     //    32 f32 : b2 * L2E
constexpr int   WS_W3    = 29056;     //    32 f32 : W3 * LN2
constexpr int   WS_BYTES = 29184;

constexpr float L2E = 1.4426950408889634f;
constexpr float LN2 = 0.6931471805599453f;

// PAIRS i/j packed 3 bits per pair (15 pairs; shifts >=45 yield 0 -> safe)
constexpr unsigned long long I_BITS =
  (0ull<<0)|(0ull<<3)|(0ull<<6)|(0ull<<9)|(0ull<<12)|
  (1ull<<15)|(1ull<<18)|(1ull<<21)|(1ull<<24)|
  (2ull<<27)|(2ull<<30)|(2ull<<33)|
  (3ull<<36)|(3ull<<39)|(4ull<<42);
constexpr unsigned long long J_BITS =
  (1ull<<0)|(2ull<<3)|(3ull<<6)|(4ull<<9)|(5ull<<12)|
  (2ull<<15)|(3ull<<18)|(4ull<<21)|(5ull<<24)|
  (3ull<<27)|(4ull<<30)|(5ull<<33)|
  (4ull<<36)|(5ull<<39)|(5ull<<42);

__device__ __forceinline__ float sp2(float s) {       // log2(1+exp2(s))
  float t = __builtin_amdgcn_exp2f(s);
  return __builtin_amdgcn_logf(1.0f + t);             // v_log_f32 = log2
}

__device__ __forceinline__ __half2 h1pair(__half2 u, __half2 a, __half2 b,
                                          __half2 one2) {
  __half2 s = __hadd2(__hadd2(u, a), b);
  __half2 t = h2exp2(s);                              // |s|<~8 -> safe in f16
  return h2log2(__hadd2(one2, t));
}

// ------------------------- prep: weights -> d_ws ---------------------------
__global__ __launch_bounds__(256)
void prep(const float* __restrict__ W1, const float* __restrict__ b1,
          const float* __restrict__ W2, const float* __restrict__ b2,
          const float* __restrict__ W3, char* __restrict__ ws)
{
  const int t = (int)(blockIdx.x * blockDim.x + threadIdx.x);   // 0..16383
  uint16_t* w1t = (uint16_t*)(ws + WS_W1T);
  uint16_t* w2t = (uint16_t*)(ws + WS_W2T);
  float*    b1s = (float*)(ws + WS_B1);
  float*    b2s = (float*)(ws + WS_B2);
  float*    w3s = (float*)(ws + WS_W3);
  if (t < 12288) {
    const int d = t >> 6, n = t & 63;                 // W1 is [d=192][n=64]
    const int slab = d >> 6;
    w1t[(slab * 64 + n) * 64 + (d & 63)] =
        __half_as_ushort(__float2half(W1[t] * L2E));
  } else if (t < 14336) {
    const int e = t - 12288;                          // W2 is [k=64][m=32]
    const int k = e >> 5, m = e & 31;
    w2t[m * 64 + k] = __half_as_ushort(__float2half(W2[e]));
  } else if (t < 14400) {
    b1s[t - 14336] = b1[t - 14336] * L2E;
  } else if (t < 14432) {
    b2s[t - 14400] = b2[t - 14400] * L2E;
  } else if (t < 14464) {
    w3s[t - 14432] = W3[t - 14432] * LN2;
  }
}

// ------------------------------ main kernel --------------------------------
__global__ __launch_bounds__(NT, 8)
void tb_fused(const float* __restrict__ core, const float* __restrict__ ligs,
              const float* __restrict__ b3,   const char* __restrict__ ws,
              float* __restrict__ out)
{
  extern __shared__ char smem[];
  const int tid  = (int)threadIdx.x;
  const int lane = tid & 63;
  const int ln   = lane & 15;        // fragment column
  const int qd   = lane >> 4;        // fragment quad
  const int wv   = __builtin_amdgcn_readfirstlane(tid >> 6);  // 0..15
  const int b0   = (int)blockIdx.x * BPB;

  const uint16_t* w2t = (const uint16_t*)(ws + WS_W2T);
  const float*    b1s = (const float*)(ws + WS_B1);
  const float*    b2s = (const float*)(ws + WS_B2);
  const float*    w3s = (const float*)(ws + WS_W3);

  float* yred = (float*)(smem + Y_OFF);

  // ---- stage W1T (compact ws rows of 64 halves -> LDS rows of stride 72) --
  #pragma unroll
  for (int rep = 0; rep < 3; ++rep) {
    const int c   = tid + rep * NT;                   // < 3072 always
    const int row = c >> 4, col = c & 15;
    *(uint2*)(smem + WT_OFF + row * (WT_RS * 2) + col * 8) =
        *(const uint2*)(ws + WS_W1T + row * 128 + col * 8);
  }
  if (tid < BPB) yred[tid] = 0.0f;
  __syncthreads();                                    // barrier #1: W1T ready

  // ------------- Phase 1: 14 jobs = (xr 0..6) x (mt 0..1), 1 per wave -----
  if (wv < 14) {
    const int xr = wv >> 1;
    const int mt = wv & 1;
    const float* src = (xr == 0)
        ? (core + (size_t)(b0 + mt * 16 + ln) * 64)
        : (ligs + ((size_t)(b0 + mt * 16 + ln) * 6 + (size_t)(xr - 1)) * 64);

    union AF { f16x8 v; fp16v2 p[4]; } Afr[2];
    #pragma unroll
    for (int ks = 0; ks < 2; ++ks) {
      const float4 f0 = *(const float4*)(src + ks * 32 + qd * 8);
      const float4 f1 = *(const float4*)(src + ks * 32 + qd * 8 + 4);
      Afr[ks].p[0] = __builtin_amdgcn_cvt_pkrtz(f0.x, f0.y);
      Afr[ks].p[1] = __builtin_amdgcn_cvt_pkrtz(f0.z, f0.w);
      Afr[ks].p[2] = __builtin_amdgcn_cvt_pkrtz(f1.x, f1.y);
      Afr[ks].p[3] = __builtin_amdgcn_cvt_pkrtz(f1.z, f1.w);
    }

    const int sl_lo = (xr == 0) ? 0 : 1;
    const int sl_hi = (xr == 0) ? 0 : 2;
    #pragma unroll 1
    for (int sl = sl_lo; sl <= sl_hi; ++sl) {
      const int trow = (xr == 0) ? 0 : ((sl == 1) ? xr : 6 + xr);
      #pragma unroll
      for (int nt = 0; nt < 4; ++nt) {
        const float bias = (trow == 0) ? b1s[nt * 16 + ln] : 0.0f;
        f32x4 c = {bias, bias, bias, bias};           // b1 folded into C-init
        #pragma unroll
        for (int ks = 0; ks < 2; ++ks) {
          const f16x8 Bf = *(const f16x8*)(smem + WT_OFF +
              ((sl * 64 + nt * 16 + ln) * WT_RS + ks * 32 + qd * 8) * 2);
          c = __builtin_amdgcn_mfma_f32_16x16x32_f16(Afr[ks].v, Bf, c, 0, 0, 0);
        }
        #pragma unroll
        for (int reg = 0; reg < 4; ++reg) {
          const int b = mt * 16 + qd * 4 + reg;       // C row = batch-local b
          *(uint16_t*)(smem + (size_t)b * T_STRIDE + trow * 128 + (nt * 16 + ln) * 2) =
              __half_as_ushort(__float2half(c[reg]));
        }
      }
    }
  }

  // W2 B-frags + epilogue consts (global, L2-hot) — overlaps Phase-1 tail
  f16x8 W2f[2][2];
  #pragma unroll
  for (int nt = 0; nt < 2; ++nt)
    #pragma unroll
    for (int ks = 0; ks < 2; ++ks)
      W2f[nt][ks] = *(const f16x8*)(w2t + (nt * 16 + ln) * 64 + ks * 32 + qd * 8);
  float b2v[2], w3v[2];
  #pragma unroll
  for (int nt = 0; nt < 2; ++nt) {
    b2v[nt] = b2s[nt * 16 + ln];
    w3v[nt] = w3s[nt * 16 + ln];
  }

  __syncthreads();                                    // barrier #2: T ready

  // ------------- Phase 2: 60 units (30 q x 2 mt) over 16 waves ------------
  const int mtw = wv & 1;
  const int qr  = wv >> 1;                            // 0..7
  const __half2 one2 = __float2half2_rn(1.0f);
  const char* Tb  = smem + (size_t)(mtw * 16 + ln) * T_STRIDE;
  const int koff  = qd * 16;

  union U4 { u32x4 u; __half2 h[4]; };
  U4 hu0, hu1;                                        // u row: loop-invariant
  hu0.u = *(const u32x4*)(Tb + koff);
  hu1.u = *(const u32x4*)(Tb + 64 + koff);

  float yacc[4] = {0.f, 0.f, 0.f, 0.f};

  #pragma unroll
  for (int t3 = 0; t3 < 4; ++t3) {
    const int q = qr + 8 * t3;                        // <= 31
    const float msk = (q < 30) ? 1.0f : 0.0f;         // wave-uniform mask
    const int p  = q >> 1;
    const int iv = (int)((I_BITS >> (3 * p)) & 7ull); // p=15 -> 0 (safe)
    const int jv = (int)((J_BITS >> (3 * p)) & 7ull);
    const int An = (q & 1) ? jv : iv;
    const int Bn = (q & 1) ? iv : jv;
    const char* TA = Tb + (1 + An) * 128;
    const char* TB = Tb + (7 + Bn) * 128;

    U4 da0, db0, da1, db1;
    da0.u = *(const u32x4*)(TA + koff);
    db0.u = *(const u32x4*)(TB + koff);
    da1.u = *(const u32x4*)(TA + 64 + koff);
    db1.u = *(const u32x4*)(TB + 64 + koff);

    union { f16x8 v; __half2 h[4]; } A0, A1;
    #pragma unroll
    for (int w = 0; w < 4; ++w) A0.h[w] = h1pair(hu0.h[w], da0.h[w], db0.h[w], one2);
    #pragma unroll
    for (int w = 0; w < 4; ++w) A1.h[w] = h1pair(hu1.h[w], da1.h[w], db1.h[w], one2);

    f32x4 c0 = {0.f, 0.f, 0.f, 0.f};
    f32x4 c1 = {0.f, 0.f, 0.f, 0.f};
    c0 = __builtin_amdgcn_mfma_f32_16x16x32_f16(A0.v, W2f[0][0], c0, 0, 0, 0);
    c0 = __builtin_amdgcn_mfma_f32_16x16x32_f16(A1.v, W2f[0][1], c0, 0, 0, 0);
    c1 = __builtin_amdgcn_mfma_f32_16x16x32_f16(A0.v, W2f[1][0], c1, 0, 0, 0);
    c1 = __builtin_amdgcn_mfma_f32_16x16x32_f16(A1.v, W2f[1][1], c1, 0, 0, 0);

    #pragma unroll
    for (int reg = 0; reg < 4; ++reg) {
      yacc[reg] += msk * (sp2(c0[reg] + b2v[0]) * w3v[0]
                        + sp2(c1[reg] + b2v[1]) * w3v[1]);
    }
  }

  // reduce over the 16 fragment columns (ln) inside each quad group
  #pragma unroll
  for (int reg = 0; reg < 4; ++reg) {
    float v = yacc[reg];
    v += __shfl_xor(v, 1);
    v += __shfl_xor(v, 2);
    v += __shfl_xor(v, 4);
    v += __shfl_xor(v, 8);
    yacc[reg] = v;
  }
  if (ln == 0) {
    #pragma unroll
    for (int reg = 0; reg < 4; ++reg)
      atomicAdd(&yred[mtw * 16 + qd * 4 + reg], yacc[reg]);
  }
  __syncthreads();
  if (tid < BPB) out[b0 + tid] = 0.5f * yred[tid] + 15.0f * b3[0];
}

extern "C" void kernel_launch(void* const* d_in, const int* in_sizes, int n_in,
                              void* d_out, int out_size, void* d_ws, size_t ws_size,
                              hipStream_t stream) {
  const float* core = (const float*)d_in[0];
  const float* ligs = (const float*)d_in[1];
  const float* W1   = (const float*)d_in[2];
  const float* b1   = (const float*)d_in[3];
  const float* W2   = (const float*)d_in[4];
  const float* b2   = (const float*)d_in[5];
  const float* W3   = (const float*)d_in[6];
  const float* b3   = (const float*)d_in[7];
  float* out = (float*)d_out;
  char*  ws  = (char*)d_ws;                 // needs WS_BYTES (29 KB) scratch

  const int B = in_sizes[0] / 64;           // 32768
  const int grid = B / BPB;                 // 1024

  prep<<<dim3(57), dim3(256), 0, stream>>>(W1, b1, W2, b2, W3, ws);

  (void)hipFuncSetAttribute((const void*)tb_fused,
                            hipFuncAttributeMaxDynamicSharedMemorySize, LDS_BYTES);
  tb_fused<<<dim3(grid), dim3(NT), LDS_BYTES, stream>>>(
      core, ligs, b3, ws, out);
}